// Round 1
// baseline (1368.462 us; speedup 1.0000x reference)
//
#include <hip/hip_runtime.h>
#include <hip/hip_bf16.h>

// Problem constants (match reference)
#define THRESH 0.05f
constexpr int B_   = 32;
constexpr int CIN  = 128;
constexpr int COUT = 256;
constexpr int HH   = 56;
constexpr int WW   = 56;
constexpr int HWSZ = HH * WW;           // 3136
constexpr int WELEM = COUT * CIN * 9;   // 294912 weight elements

// ---------------------------------------------------------------------------
// Kernel 1: maxabs of weight — single block, 1024 threads, shuffle+LDS reduce
// ---------------------------------------------------------------------------
__global__ __launch_bounds__(1024) void maxabs_kernel(const float* __restrict__ w,
                                                      float* __restrict__ out) {
    float m = 0.0f;
    for (int i = threadIdx.x; i < WELEM; i += 1024)
        m = fmaxf(m, fabsf(w[i]));
    // wave(64) butterfly
    #pragma unroll
    for (int off = 32; off > 0; off >>= 1)
        m = fmaxf(m, __shfl_xor(m, off));
    __shared__ float s[16];
    if ((threadIdx.x & 63) == 0) s[threadIdx.x >> 6] = m;
    __syncthreads();
    if (threadIdx.x < 16) {
        m = s[threadIdx.x];
        #pragma unroll
        for (int off = 8; off > 0; off >>= 1)
            m = fmaxf(m, __shfl_xor(m, off));
        if (threadIdx.x == 0) out[0] = m;
    }
}

// ---------------------------------------------------------------------------
// Kernel 2: faithful ternary quantization into d_ws (fp32, OIHW layout)
//   nw = w / maxabs
//   mask = where((nw > -t) & (nw <= t), 0, nw); mask = where(mask> t, 1, mask)
//   mask = where(mask < -t, -1, mask);  qw = where(mask == -1, Wn, mask)
// ---------------------------------------------------------------------------
__global__ __launch_bounds__(256) void quant_kernel(const float* __restrict__ w,
                                                    const float* __restrict__ maxabs,
                                                    const float* __restrict__ Wn,
                                                    float* __restrict__ qw) {
    int i = blockIdx.x * 256 + threadIdx.x;
    if (i >= WELEM) return;
    float mx = maxabs[0];
    float nw = w[i] / mx;                 // true division (matches jnp)
    float m  = (nw > -THRESH && nw <= THRESH) ? 0.0f : nw;
    if (m >  THRESH) m =  1.0f;
    if (m < -THRESH) m = -1.0f;
    qw[i] = (m == -1.0f) ? Wn[0] : m;
}

// ---------------------------------------------------------------------------
// Kernel 3: direct conv. One thread -> one spatial position p, 8 consecutive
// output channels. Weight indices are block-uniform -> scalar loads (SGPR),
// so the inner loop is 9 vector loads + 72 v_fmac per ci.
// grid = (ceil(3136/256)=13, COUT/8=32, B=32), block = 256
// ---------------------------------------------------------------------------
__global__ __launch_bounds__(256) void conv_kernel(const float* __restrict__ X,
                                                   const float* __restrict__ qw,
                                                   float* __restrict__ out) {
    const int p   = blockIdx.x * 256 + threadIdx.x;
    const int n   = blockIdx.z;
    const int co0 = blockIdx.y * 8;
    if (p >= HWSZ) return;
    const int h = p / WW;
    const int w = p - h * WW;

    float acc[8] = {0.f, 0.f, 0.f, 0.f, 0.f, 0.f, 0.f, 0.f};

    const float* xbase = X  + (size_t)n * CIN * HWSZ;
    const float* wbase = qw + (size_t)co0 * CIN * 9;

    for (int ci = 0; ci < CIN; ++ci) {
        // gather the 3x3 input window (zero outside)
        float xv[9];
        const float* xp = xbase + (size_t)ci * HWSZ;
        #pragma unroll
        for (int dh = 0; dh < 3; ++dh) {
            const int y = h + dh - 1;
            const bool yok = (unsigned)y < (unsigned)HH;
            #pragma unroll
            for (int dw = 0; dw < 3; ++dw) {
                const int x = w + dw - 1;
                const bool ok = yok && ((unsigned)x < (unsigned)WW);
                xv[dh * 3 + dw] = ok ? xp[y * WW + x] : 0.0f;
            }
        }
        // 8 output channels; weight addresses are wave-uniform
        #pragma unroll
        for (int j = 0; j < 8; ++j) {
            const float* wj = wbase + ((size_t)j * CIN + ci) * 9;
            #pragma unroll
            for (int t = 0; t < 9; ++t)
                acc[j] = fmaf(wj[t], xv[t], acc[j]);
        }
    }

    float* op = out + ((size_t)(n * COUT + co0)) * HWSZ + p;
    #pragma unroll
    for (int j = 0; j < 8; ++j)
        op[(size_t)j * HWSZ] = acc[j];
}

// ---------------------------------------------------------------------------
// Launch
// ---------------------------------------------------------------------------
extern "C" void kernel_launch(void* const* d_in, const int* in_sizes, int n_in,
                              void* d_out, int out_size, void* d_ws, size_t ws_size,
                              hipStream_t stream) {
    const float* X      = (const float*)d_in[0];
    const float* weight = (const float*)d_in[1];
    // const float* Wp  = (const float*)d_in[2];   // never enters forward (faithful)
    const float* Wn     = (const float*)d_in[3];
    float* out = (float*)d_out;

    // workspace layout: [0] = maxabs, [16..] = quantized weights (294912 f32)
    float* ws_maxabs = (float*)d_ws;
    float* ws_qw     = (float*)d_ws + 16;

    maxabs_kernel<<<1, 1024, 0, stream>>>(weight, ws_maxabs);
    quant_kernel<<<(WELEM + 255) / 256, 256, 0, stream>>>(weight, ws_maxabs, Wn, ws_qw);

    dim3 grid((HWSZ + 255) / 256, COUT / 8, B_);
    conv_kernel<<<grid, 256, 0, stream>>>(X, ws_qw, out);
}

// Round 2
// 106.555 us; speedup vs baseline: 12.8428x; 12.8428x over previous
//
#include <hip/hip_runtime.h>
#include <hip/hip_bf16.h>

#define THRESH 0.05f
constexpr int B_   = 32;
constexpr int CIN  = 128;
constexpr int COUT = 256;
constexpr int HH   = 56;
constexpr int WW   = 56;
constexpr int HWSZ = HH * WW;            // 3136
constexpr int WELEM = COUT * CIN * 9;    // 294912

typedef unsigned short u16;
typedef __attribute__((ext_vector_type(4))) float  f32x4;
typedef __attribute__((ext_vector_type(8))) short  s16x8;   // 8 bf16 = 4 VGPRs

static __device__ __forceinline__ u16 f2bf(float f) {
    __hip_bfloat16 h = __float2bfloat16(f);
    return *reinterpret_cast<u16*>(&h);
}

// ---------------------------------------------------------------------------
// Kernel 1: per-block maxabs partials (256 blocks x 256 thr)
// ---------------------------------------------------------------------------
__global__ __launch_bounds__(256) void maxabs_part(const float* __restrict__ w,
                                                   float* __restrict__ partial) {
    int tid = threadIdx.x;
    float m = 0.0f;
    for (int i = blockIdx.x * 256 + tid; i < WELEM; i += 256 * 256)
        m = fmaxf(m, fabsf(w[i]));
    #pragma unroll
    for (int off = 32; off > 0; off >>= 1) m = fmaxf(m, __shfl_xor(m, off));
    __shared__ float s[4];
    if ((tid & 63) == 0) s[tid >> 6] = m;
    __syncthreads();
    if (tid == 0) partial[blockIdx.x] = fmaxf(fmaxf(s[0], s[1]), fmaxf(s[2], s[3]));
}

// ---------------------------------------------------------------------------
// Kernel 2: reduce partials + faithful ternary quantize + pack bf16
// A_pack layout: [co][tap(9)][ci(128)]   (k = tap*CK + ci within chunks)
// 1152 blocks x 256 thr  (covers WELEM exactly)
// ---------------------------------------------------------------------------
__global__ __launch_bounds__(256) void quant_pack(const float* __restrict__ w,
                                                  const float* __restrict__ partial,
                                                  const float* __restrict__ Wn,
                                                  u16* __restrict__ Apack) {
    int tid = threadIdx.x;
    float m = partial[tid];
    #pragma unroll
    for (int off = 32; off > 0; off >>= 1) m = fmaxf(m, __shfl_xor(m, off));
    __shared__ float s[4];
    if ((tid & 63) == 0) s[tid >> 6] = m;
    __syncthreads();
    const float mx = fmaxf(fmaxf(s[0], s[1]), fmaxf(s[2], s[3]));
    const float wn = Wn[0];

    int idx = blockIdx.x * 256 + tid;          // input index: ((co*128+ci)*9+tap)
    float nw = w[idx] / mx;
    float q  = (nw > -THRESH && nw <= THRESH) ? 0.0f : nw;
    if (q >  THRESH) q =  1.0f;
    if (q < -THRESH) q = -1.0f;
    if (q == -1.0f)  q = wn;

    int tap = idx % 9;
    int r   = idx / 9;
    int ci  = r % CIN;
    int co  = r / CIN;
    Apack[(co * 9 + tap) * CIN + ci] = f2bf(q);
}

// ---------------------------------------------------------------------------
// Kernel 3: X (NCHW f32) -> Xt[n][h][w][ci] bf16 via LDS transpose
// grid = 32 * 49 blocks (64 positions each), block = 256
// ---------------------------------------------------------------------------
__global__ __launch_bounds__(256) void x_to_bf16t(const float* __restrict__ X,
                                                  u16* __restrict__ Xt) {
    __shared__ u16 T[64 * 136];                // pad 128 -> 136
    const int b  = blockIdx.x;
    const int n  = b / 49, pt = b - n * 49;
    const int p0 = pt * 64;
    const int tid = threadIdx.x;
    const int ci  = tid >> 1, h2 = tid & 1;

    const float* src = X + ((size_t)(n * CIN + ci)) * HWSZ + p0 + h2 * 32;
    #pragma unroll
    for (int j = 0; j < 8; ++j) {
        f32x4 v = *(const f32x4*)(src + j * 4);
        #pragma unroll
        for (int mth = 0; mth < 4; ++mth)
            T[(h2 * 32 + j * 4 + mth) * 136 + ci] = f2bf(v[mth]);
    }
    __syncthreads();
    #pragma unroll
    for (int k = 0; k < 4; ++k) {
        int idx = tid + k * 256;
        int p = idx >> 4, c8 = idx & 15;
        s16x8 v = *(const s16x8*)&T[p * 136 + c8 * 8];
        *(s16x8*)(Xt + ((size_t)(n * HWSZ + p0 + p)) * CIN + c8 * 8) = v;
    }
}

// ---------------------------------------------------------------------------
// Kernel 4: implicit-GEMM conv via MFMA 16x16x32 bf16
// Block: 256 thr / 4 waves. Output tile: 64 co x (4 rows x 56 cols, N=256 pad)
// Wave w owns output row h0+w. K = 1152 in 4 chunks of (9 taps x 32 ci).
// grid = (4 co_tiles, 14 row_tiles, 32 images)
// ---------------------------------------------------------------------------
__global__ __launch_bounds__(256, 2) void conv_mfma(const u16* __restrict__ Xt,
                                                    const u16* __restrict__ Apack,
                                                    float* __restrict__ out) {
    __shared__ u16 Alds[64 * 296];             // [64 co][288 k] pad ->296 (592B stride)
    __shared__ u16 Xs[6 * 66 * 40];            // [6 rows][66 cols][32 ci pad->40]

    const int tid  = threadIdx.x;
    const int wid  = tid >> 6;
    const int lane = tid & 63;
    const int r16  = lane & 15;                // A row / B col / D col
    const int g    = lane >> 4;                // k-group: k_off = g*8

    const int co0 = blockIdx.x * 64;
    const int h0  = blockIdx.y * 4;
    const int n   = blockIdx.z;

    f32x4 acc[4][4];
    #pragma unroll
    for (int i = 0; i < 4; ++i)
        #pragma unroll
        for (int j = 0; j < 4; ++j) acc[i][j] = (f32x4){0.f, 0.f, 0.f, 0.f};

    for (int cc = 0; cc < 4; ++cc) {           // ci chunks of 32
        // ---- stage A: 64 rows x 288 k  (2304 x 16B, 9 per thread, exact)
        #pragma unroll
        for (int i = 0; i < 9; ++i) {
            int idx = tid + i * 256;
            int row = idx / 36, seg = idx - row * 36;
            int tap = seg >> 2, g8 = seg & 3;
            s16x8 v = *(const s16x8*)(Apack + (size_t)(co0 + row) * 1152
                                      + tap * 128 + cc * 32 + g8 * 8);
            *(s16x8*)&Alds[row * 296 + tap * 32 + g8 * 8] = v;
        }
        // ---- stage B: 6x58 sites x 32 ci (1392 x 16B), halo zero-filled
        #pragma unroll
        for (int i = 0; i < 6; ++i) {
            int idx = tid + i * 256;
            if (idx < 1392) {
                int site = idx >> 2, g8 = idx & 3;
                int r = site / 58, c = site - r * 58;
                int hr = h0 - 1 + r, wc = c - 1;
                s16x8 v = (s16x8){0, 0, 0, 0, 0, 0, 0, 0};
                if ((unsigned)hr < (unsigned)HH && (unsigned)wc < (unsigned)WW)
                    v = *(const s16x8*)(Xt + ((size_t)(n * HWSZ + hr * WW + wc)) * CIN
                                        + cc * 32 + g8 * 8);
                *(s16x8*)&Xs[(r * 66 + c) * 40 + g8 * 8] = v;
            }
        }
        __syncthreads();

        // ---- compute: 9 taps x (4 A-frags + 4 B-frags + 16 MFMA)
        #pragma unroll
        for (int t = 0; t < 9; ++t) {
            const int dh = t / 3, dw = t % 3;
            s16x8 af[4], bf[4];
            #pragma unroll
            for (int mf = 0; mf < 4; ++mf)
                af[mf] = *(const s16x8*)&Alds[(mf * 16 + r16) * 296 + t * 32 + g * 8];
            #pragma unroll
            for (int nf = 0; nf < 4; ++nf)
                bf[nf] = *(const s16x8*)&Xs[((wid + dh) * 66 + nf * 16 + r16 + dw) * 40 + g * 8];
            #pragma unroll
            for (int mf = 0; mf < 4; ++mf)
                #pragma unroll
                for (int nf = 0; nf < 4; ++nf)
                    acc[mf][nf] = __builtin_amdgcn_mfma_f32_16x16x32_bf16(
                        af[mf], bf[nf], acc[mf][nf], 0, 0, 0);
        }
        __syncthreads();
    }

    // ---- store: D col = lane&15 (spatial), row = g*4+j (co)
    const int h = h0 + wid;
    float* obase = out + ((size_t)(n * COUT + co0)) * HWSZ + h * WW;
    #pragma unroll
    for (int mf = 0; mf < 4; ++mf)
        #pragma unroll
        for (int nf = 0; nf < 4; ++nf) {
            int col = nf * 16 + r16;
            if (col < WW) {
                #pragma unroll
                for (int j = 0; j < 4; ++j) {
                    int co = mf * 16 + g * 4 + j;
                    obase[(size_t)co * HWSZ + col] = acc[mf][nf][j];
                }
            }
        }
}

// ---------------------------------------------------------------------------
// Launch
// ---------------------------------------------------------------------------
extern "C" void kernel_launch(void* const* d_in, const int* in_sizes, int n_in,
                              void* d_out, int out_size, void* d_ws, size_t ws_size,
                              hipStream_t stream) {
    const float* X      = (const float*)d_in[0];
    const float* weight = (const float*)d_in[1];
    // Wp (d_in[2]) never enters the forward (faithful to source)
    const float* Wn     = (const float*)d_in[3];
    float* out = (float*)d_out;

    float* ws_partial = (float*)d_ws;                        // 256 f32
    u16*   ws_apack   = (u16*)((char*)d_ws + 4096);          // 294912 bf16 (~576 KB)
    u16*   ws_xt      = (u16*)((char*)d_ws + (1 << 20));     // 100352*128 bf16 (~24.5 MB)

    maxabs_part<<<256, 256, 0, stream>>>(weight, ws_partial);
    quant_pack<<<WELEM / 256, 256, 0, stream>>>(weight, ws_partial, Wn, ws_apack);
    x_to_bf16t<<<B_ * (HWSZ / 64), 256, 0, stream>>>(X, ws_xt);

    dim3 grid(COUT / 64, HH / 4, B_);
    conv_mfma<<<grid, 256, 0, stream>>>(ws_xt, ws_apack, out);
}